// Round 1
// baseline (279.987 us; speedup 1.0000x reference)
//
#include <hip/hip_runtime.h>
#include <math.h>

#define BB    1024
#define CC    256
#define HWN   361
#define SEH   64
#define P3C   768

// ---------------- Kernel 1: pooling (mean over HW, masked max over HW) ----------
// One wave (64 lanes) per (b,c) row of 361 contiguous floats. 4 waves/block.
__global__ __launch_bounds__(256) void k_pool(const float* __restrict__ x,
                                              const float* __restrict__ mask,
                                              const float* __restrict__ msum,
                                              const float* __restrict__ msqrt,
                                              float* __restrict__ pooled) {
    const int wave = threadIdx.x >> 6;
    const int lane = threadIdx.x & 63;
    const int row  = blockIdx.x * 4 + wave;       // row = b*CC + c
    const int b    = row >> 8;
    const int c    = row & 255;

    const float* xr = x    + (size_t)row * HWN;
    const float* mr = mask + (size_t)b   * HWN;

    float s  = 0.0f;
    float mx = -INFINITY;
    #pragma unroll
    for (int i = lane; i < HWN; i += 64) {
        float v = xr[i];
        float m = mr[i];
        s += v;                                    // raw sum (unmasked, per reference)
        mx = fmaxf(mx, v + (1.0f - m) * (-5000.0f));
    }
    // 64-lane butterfly reduce
    #pragma unroll
    for (int off = 32; off; off >>= 1) {
        s  += __shfl_xor(s, off);
        mx  = fmaxf(mx, __shfl_xor(mx, off));
    }
    if (lane == 0) {
        float d      = msum[b];
        float mean   = s / d;
        float bscale = (msqrt[b] - 14.0f) * 0.1f;  // (sqrt(div) - B_AVG)/10
        float* pr = pooled + (size_t)b * P3C;
        pr[c]       = mean;
        pr[256 + c] = mean * bscale;
        pr[512 + c] = mx;
    }
}

// ---------------- Kernel 2: tiny MLP  hid=relu(pooled@w1.T+b1); se=hid@w2.T+b2 ---
// 4 batch rows per block. Writes sigmoid(gamma) and beta.
__global__ __launch_bounds__(256) void k_mlp(const float* __restrict__ pooled,
                                             const float* __restrict__ w1,
                                             const float* __restrict__ b1,
                                             const float* __restrict__ w2,
                                             const float* __restrict__ b2,
                                             float* __restrict__ gsig,
                                             float* __restrict__ beta) {
    __shared__ float plds[4 * P3C];   // 12 KB
    __shared__ float hlds[4 * SEH];   // 1 KB
    const int t  = threadIdx.x;
    const int b0 = blockIdx.x * 4;

    // cooperative coalesced load of 4 pooled rows
    #pragma unroll
    for (int i = 0; i < 12; ++i) {
        int idx = t + i * 256;
        plds[idx] = pooled[(size_t)b0 * P3C + idx];
    }
    __syncthreads();

    // layer 1: thread (bb, s): hid[bb][s]
    {
        const int bb = t >> 6, s = t & 63;
        float acc = b1[s];
        const float* w1r = w1   + s  * P3C;
        const float* pr  = plds + bb * P3C;
        #pragma unroll 8
        for (int j = 0; j < P3C; ++j) acc = fmaf(pr[j], w1r[j], acc);
        hlds[bb * SEH + s] = fmaxf(acc, 0.0f);
    }
    __syncthreads();

    // layer 2: 4 rows x 512 outputs = 2048 dots; 8 per thread
    #pragma unroll
    for (int k = 0; k < 8; ++k) {
        int q  = k * 256 + t;
        int rb = q >> 9;          // batch sub-row 0..3
        int o  = q & 511;         // output 0..511
        float a2 = b2[o];
        const float* w2r = w2   + o  * SEH;
        const float* hr  = hlds + rb * SEH;
        #pragma unroll 8
        for (int ss = 0; ss < SEH; ++ss) a2 = fmaf(hr[ss], w2r[ss], a2);
        int b = b0 + rb;
        if (o < 256) gsig[(size_t)b * 256 + o]        = 1.0f / (1.0f + __expf(-a2));
        else         beta[(size_t)b * 256 + (o - 256)] = a2;
    }
}

// ---------------- Kernel 3: apply  out = (sigmoid(g)*x + beta) * mask ----------
__global__ __launch_bounds__(256) void k_apply(const float* __restrict__ x,
                                               const float* __restrict__ mask,
                                               const float* __restrict__ gsig,
                                               const float* __restrict__ beta,
                                               float* __restrict__ out) {
    const int wave = threadIdx.x >> 6;
    const int lane = threadIdx.x & 63;
    const int row  = blockIdx.x * 4 + wave;       // row = b*CC + c
    const int b    = row >> 8;

    const float g  = gsig[row];
    const float be = beta[row];
    const float* xr = x    + (size_t)row * HWN;
    const float* mr = mask + (size_t)b   * HWN;
    float*       orow = out + (size_t)row * HWN;

    #pragma unroll
    for (int i = lane; i < HWN; i += 64) {
        float v = xr[i];
        float m = mr[i];
        orow[i] = fmaf(g, v, be) * m;
    }
}

extern "C" void kernel_launch(void* const* d_in, const int* in_sizes, int n_in,
                              void* d_out, int out_size, void* d_ws, size_t ws_size,
                              hipStream_t stream) {
    const float* x     = (const float*)d_in[0];
    const float* mask  = (const float*)d_in[1];
    const float* msum  = (const float*)d_in[2];
    const float* msqrt = (const float*)d_in[3];
    const float* w1    = (const float*)d_in[4];
    const float* b1    = (const float*)d_in[5];
    const float* w2    = (const float*)d_in[6];
    const float* b2    = (const float*)d_in[7];
    float* out = (float*)d_out;

    float* pooled = (float*)d_ws;                 // B*768 f32  (3 MB)
    float* gsig   = pooled + (size_t)BB * P3C;    // B*256 f32  (1 MB)
    float* beta   = gsig   + (size_t)BB * 256;    // B*256 f32  (1 MB)

    k_pool <<<BB * CC / 4, 256, 0, stream>>>(x, mask, msum, msqrt, pooled);
    k_mlp  <<<BB / 4,      256, 0, stream>>>(pooled, w1, b1, w2, b2, gsig, beta);
    k_apply<<<BB * CC / 4, 256, 0, stream>>>(x, mask, gsig, beta, out);
}